// Round 1
// baseline (4308.794 us; speedup 1.0000x reference)
//
#include <hip/hip_runtime.h>

#define DD 64
#define NUM_GRAPHS 64

// ---- degree: deg[c] += 1 per edge (self-loop +1 folded into k_dinv) ----
__global__ void k_deg(const int* __restrict__ col, float* __restrict__ deg, int E) {
    int i = blockIdx.x * blockDim.x + threadIdx.x;
    if (i < E) atomicAdd(&deg[col[i]], 1.0f);
}

__global__ void k_dinv(float* __restrict__ deg, int N) {
    int i = blockIdx.x * blockDim.x + threadIdx.x;
    if (i < N) deg[i] = 1.0f / sqrtf(deg[i] + 1.0f);   // +1 = self loop; always > 0
}

// ---- embedding gather: X[i][j] = emb[node_types[i]][j] ----
__global__ void k_embed(const int* __restrict__ nt, const float* __restrict__ emb,
                        float* __restrict__ X, int N) {
    long t = (long)blockIdx.x * blockDim.x + threadIdx.x;
    if (t >= (long)N * DD) return;
    int i = (int)(t >> 6), j = (int)(t & 63);
    X[t] = emb[nt[i] * DD + j];
}

// ---- in-place row transform: X[i] <- X[i] @ W  (W staged in LDS) ----
__global__ __launch_bounds__(256) void k_matmul_inplace(float* __restrict__ X,
                                                        const float* __restrict__ W, int N) {
    __shared__ float Ws[DD * DD];   // 16 KB
    __shared__ float xs[4][DD];
    int tid = threadIdx.x;
    for (int k = tid; k < DD * DD; k += 256) Ws[k] = W[k];
    int j = tid & 63, r = tid >> 6;              // 4 nodes per block-iteration
    long stride = (long)gridDim.x * 4;
    for (long base = (long)blockIdx.x * 4; base < N; base += stride) {
        long node = base + r;
        __syncthreads();                          // covers Ws load on iter 0, xs reuse after
        xs[r][j] = (node < (long)N) ? X[node * DD + j] : 0.0f;
        __syncthreads();
        float acc = 0.0f;
        #pragma unroll
        for (int d = 0; d < DD; ++d) acc += xs[r][d] * Ws[d * DD + j];
        if (node < (long)N) X[node * DD + j] = acc;
    }
}

// ---- edge scatter: OUT[col] += H[row] * dinv[row]*dinv[col], 16 threads/edge, float4 ----
__global__ __launch_bounds__(256) void k_scatter(const int* __restrict__ row,
                                                 const int* __restrict__ col,
                                                 const float* __restrict__ dinv,
                                                 const float* __restrict__ H,
                                                 float* __restrict__ OUT, int E) {
    long t = (long)blockIdx.x * blockDim.x + threadIdx.x;
    int e = (int)(t >> 4);
    if (e >= E) return;
    int f = (int)(t & 15) * 4;
    int r = row[e], c = col[e];
    float nrm = dinv[r] * dinv[c];
    const float4 h = *(const float4*)(H + (long)r * DD + f);
    float* o = OUT + (long)c * DD + f;
    atomicAdd(o + 0, h.x * nrm);
    atomicAdd(o + 1, h.y * nrm);
    atomicAdd(o + 2, h.z * nrm);
    atomicAdd(o + 3, h.w * nrm);
}

// ---- epilogue: OUT += H * dinv^2 (self loop) + b ; optional ReLU ----
__global__ void k_epilogue(float* __restrict__ OUT, const float* __restrict__ H,
                           const float* __restrict__ dinv, const float* __restrict__ b,
                           int N, int do_relu) {
    long t = (long)blockIdx.x * blockDim.x + threadIdx.x;
    if (t >= (long)N * DD) return;
    int i = (int)(t >> 6), j = (int)(t & 63);
    float di = dinv[i];
    float v = OUT[t] + H[t] * di * di + b[j];
    OUT[t] = do_relu ? fmaxf(v, 0.0f) : v;
}

// ---- pooling: batch is sorted; per-thread running sum, flush on graph change ----
__global__ __launch_bounds__(256) void k_pool(const float* __restrict__ X,
                                              const int* __restrict__ batch,
                                              float* __restrict__ pool, int N) {
    const int CH = 1024;                 // nodes per block
    int j = threadIdx.x & 63, r = threadIdx.x >> 6;
    long base = (long)blockIdx.x * CH;
    if (base >= N) return;
    long end = base + CH; if (end > N) end = N;
    int cur = -1; float acc = 0.0f;
    for (long i = base + r; i < end; i += 4) {
        int g = batch[i];
        float v = X[i * DD + j];
        if (g != cur) {
            if (cur >= 0) atomicAdd(&pool[cur * DD + j], acc);
            cur = g; acc = v;
        } else {
            acc += v;
        }
    }
    if (cur >= 0) atomicAdd(&pool[cur * DD + j], acc);
}

// ---- final: mean (count via binary search on sorted batch) + row L2 normalize ----
__global__ void k_final(const float* __restrict__ pool, const int* __restrict__ batch,
                        float* __restrict__ out, int N) {
    int g = blockIdx.x, j = threadIdx.x;
    int lo = 0, hi = N;
    while (lo < hi) { int m = (lo + hi) >> 1; if (batch[m] < g) lo = m + 1; else hi = m; }
    int lo2 = lo; hi = N;
    while (lo2 < hi) { int m = (lo2 + hi) >> 1; if (batch[m] < g + 1) lo2 = m + 1; else hi = m; }
    float cnt = fmaxf((float)(lo2 - lo), 1.0f);
    float v = pool[g * DD + j] / cnt;
    float sq = v * v;
    #pragma unroll
    for (int off = 32; off > 0; off >>= 1) sq += __shfl_down(sq, off, 64);
    float nrm = __shfl(sq, 0, 64);
    out[g * DD + j] = v / sqrtf(nrm);
}

extern "C" void kernel_launch(void* const* d_in, const int* in_sizes, int n_in,
                              void* d_out, int out_size, void* d_ws, size_t ws_size,
                              hipStream_t stream) {
    const int*   node_types = (const int*)d_in[0];
    const int*   edge_index = (const int*)d_in[1];
    const int*   batch      = (const int*)d_in[2];
    const float* emb        = (const float*)d_in[3];
    const float* W1 = (const float*)d_in[4];
    const float* b1 = (const float*)d_in[5];
    const float* W2 = (const float*)d_in[6];
    const float* b2 = (const float*)d_in[7];
    const float* W3 = (const float*)d_in[8];
    const float* b3 = (const float*)d_in[9];
    const int N = in_sizes[0];
    const int E = in_sizes[1] / 2;
    const int* row = edge_index;       // edge_index is (2,E) row-major
    const int* col = edge_index + E;

    float* ws   = (float*)d_ws;
    float* dinv = ws;                              // N floats (N*4 % 16 == 0)
    float* bufA = ws + N;                          // N*DD floats
    float* bufB = bufA + (long)N * DD;             // N*DD floats
    float* pool = bufB + (long)N * DD;             // NUM_GRAPHS*DD floats

    const long ND = (long)N * DD;

    hipMemsetAsync(dinv, 0, (size_t)N * sizeof(float), stream);
    k_deg<<<(E + 255) / 256, 256, 0, stream>>>(col, dinv, E);
    k_dinv<<<(N + 255) / 256, 256, 0, stream>>>(dinv, N);

    k_embed<<<(int)((ND + 255) / 256), 256, 0, stream>>>(node_types, emb, bufA, N);

    const float* Wv[3] = {W1, W2, W3};
    const float* bv[3] = {b1, b2, b3};
    float* cur = bufA; float* nxt = bufB;
    for (int l = 0; l < 3; ++l) {
        hipMemsetAsync(nxt, 0, (size_t)ND * sizeof(float), stream);
        k_matmul_inplace<<<2048, 256, 0, stream>>>(cur, Wv[l], N);
        long T = (long)E * 16;
        k_scatter<<<(int)((T + 255) / 256), 256, 0, stream>>>(row, col, dinv, cur, nxt, E);
        k_epilogue<<<(int)((ND + 255) / 256), 256, 0, stream>>>(nxt, cur, dinv, bv[l], N,
                                                                (l < 2) ? 1 : 0);
        float* tmp = cur; cur = nxt; nxt = tmp;
    }

    hipMemsetAsync(pool, 0, (size_t)(NUM_GRAPHS * DD) * sizeof(float), stream);
    k_pool<<<(N + 1023) / 1024, 256, 0, stream>>>(cur, batch, pool, N);
    k_final<<<NUM_GRAPHS, DD, 0, stream>>>(pool, batch, (float*)d_out, N);
}

// Round 2
// 782.225 us; speedup vs baseline: 5.5084x; 5.5084x over previous
//
#include <hip/hip_runtime.h>

#define DD 64
#define NUM_GRAPHS 64
#define SCH 1024   // elements scanned per block

// ---- int degree histogram over targets ----
__global__ void k_cnt(const int* __restrict__ col, int* __restrict__ cnt, int E) {
    int i = blockIdx.x * blockDim.x + threadIdx.x;
    if (i < E) atomicAdd(&cnt[col[i]], 1);
}

__global__ void k_dinv(const int* __restrict__ cnt, float* __restrict__ dinv, int N) {
    int i = blockIdx.x * blockDim.x + threadIdx.x;
    if (i < N) dinv[i] = rsqrtf((float)cnt[i] + 1.0f);   // +1 = self loop
}

// ---- 3-kernel exclusive scan of cnt -> rowptr ----
__global__ __launch_bounds__(256) void k_scan1(const int* __restrict__ cnt,
                                               int* __restrict__ part,
                                               int* __restrict__ bsum, int N) {
    __shared__ int s[256];
    int tid = threadIdx.x;
    long base = (long)blockIdx.x * SCH + (long)tid * 4;
    int v[4]; int tot = 0;
    #pragma unroll
    for (int k = 0; k < 4; ++k) {
        long i = base + k;
        v[k] = (i < N) ? cnt[i] : 0;
        tot += v[k];
    }
    s[tid] = tot;
    __syncthreads();
    for (int off = 1; off < 256; off <<= 1) {
        int t = (tid >= off) ? s[tid - off] : 0;
        __syncthreads();
        s[tid] += t;
        __syncthreads();
    }
    if (tid == 255) bsum[blockIdx.x] = s[255];
    int excl = s[tid] - tot;
    #pragma unroll
    for (int k = 0; k < 4; ++k) {
        long i = base + k;
        if (i < N) part[i] = excl;
        excl += v[k];
    }
}

__global__ void k_scan2(int* __restrict__ bsum, int* __restrict__ rowptr, int B, int N, int E) {
    if (blockIdx.x == 0 && threadIdx.x == 0) {
        int run = 0;
        for (int i = 0; i < B; ++i) { int t = bsum[i]; bsum[i] = run; run += t; }
        rowptr[N] = E;
    }
}

__global__ void k_scan3(const int* __restrict__ part, const int* __restrict__ bsum,
                        int* __restrict__ rowptr, int N) {
    long i = (long)blockIdx.x * blockDim.x + threadIdx.x;
    if (i < N) rowptr[i] = part[i] + bsum[i / SCH];
}

// ---- CSR fill: srcidx[rowptr[c] + ticket] = row(e) ----
__global__ void k_fill(const int* __restrict__ row, const int* __restrict__ col,
                       const int* __restrict__ rowptr, int* __restrict__ fill,
                       int* __restrict__ srcidx, int E) {
    int e = blockIdx.x * blockDim.x + threadIdx.x;
    if (e >= E) return;
    int c = col[e];
    int p = rowptr[c] + atomicAdd(&fill[c], 1);
    srcidx[p] = row[e];
}

// ---- embedding gather ----
__global__ void k_embed(const int* __restrict__ nt, const float* __restrict__ emb,
                        float* __restrict__ X, int N) {
    long t = (long)blockIdx.x * blockDim.x + threadIdx.x;
    if (t >= (long)N * DD) return;
    int i = (int)(t >> 6), j = (int)(t & 63);
    X[t] = emb[nt[i] * DD + j];
}

// ---- in-place row transform: X[i] <- X[i] @ W  (W staged in LDS) ----
__global__ __launch_bounds__(256) void k_matmul_inplace(float* __restrict__ X,
                                                        const float* __restrict__ W, int N) {
    __shared__ float Ws[DD * DD];   // 16 KB
    __shared__ float xs[4][DD];
    int tid = threadIdx.x;
    for (int k = tid; k < DD * DD; k += 256) Ws[k] = W[k];
    int j = tid & 63, r = tid >> 6;
    long stride = (long)gridDim.x * 4;
    for (long base = (long)blockIdx.x * 4; base < N; base += stride) {
        long node = base + r;
        __syncthreads();
        xs[r][j] = (node < (long)N) ? X[node * DD + j] : 0.0f;
        __syncthreads();
        float acc = 0.0f;
        #pragma unroll
        for (int d = 0; d < DD; ++d) acc += xs[r][d] * Ws[d * DD + j];
        if (node < (long)N) X[node * DD + j] = acc;
    }
}

// ---- atomic-free pull aggregation, epilogue fused:
//      OUT[c] = relu?( dinv[c] * sum_e H[src_e]*dinv[src_e] + H[c]*dinv[c]^2 + b ) ----
__global__ __launch_bounds__(256) void k_aggregate(const int* __restrict__ rowptr,
                                                   const int* __restrict__ srcidx,
                                                   const float* __restrict__ dinv,
                                                   const float* __restrict__ H,
                                                   const float* __restrict__ b,
                                                   float* __restrict__ OUT,
                                                   int N, int do_relu) {
    int node = blockIdx.x * 4 + (threadIdx.x >> 6);   // one wave per node
    int j = threadIdx.x & 63;
    if (node >= N) return;
    int s = rowptr[node], e = rowptr[node + 1];
    float acc = 0.0f;
    int k = s;
    for (; k + 1 < e; k += 2) {                       // 2 independent gathers in flight
        int s0 = srcidx[k], s1 = srcidx[k + 1];
        float d0 = dinv[s0], d1 = dinv[s1];
        float h0 = H[(long)s0 * DD + j];
        float h1 = H[(long)s1 * DD + j];
        acc += h0 * d0 + h1 * d1;
    }
    if (k < e) { int s0 = srcidx[k]; acc += H[(long)s0 * DD + j] * dinv[s0]; }
    float dc = dinv[node];
    float v = acc * dc + H[(long)node * DD + j] * dc * dc + b[j];
    OUT[(long)node * DD + j] = do_relu ? fmaxf(v, 0.0f) : v;
}

// ---- pooling: batch sorted; running sum, flush on graph change ----
__global__ __launch_bounds__(256) void k_pool(const float* __restrict__ X,
                                              const int* __restrict__ batch,
                                              float* __restrict__ pool, int N) {
    const int CH = 1024;
    int j = threadIdx.x & 63, r = threadIdx.x >> 6;
    long base = (long)blockIdx.x * CH;
    if (base >= N) return;
    long end = base + CH; if (end > N) end = N;
    int cur = -1; float acc = 0.0f;
    for (long i = base + r; i < end; i += 4) {
        int g = batch[i];
        float v = X[i * DD + j];
        if (g != cur) {
            if (cur >= 0) atomicAdd(&pool[cur * DD + j], acc);
            cur = g; acc = v;
        } else {
            acc += v;
        }
    }
    if (cur >= 0) atomicAdd(&pool[cur * DD + j], acc);
}

// ---- final: mean + L2 normalize ----
__global__ void k_final(const float* __restrict__ pool, const int* __restrict__ batch,
                        float* __restrict__ out, int N) {
    int g = blockIdx.x, j = threadIdx.x;
    int lo = 0, hi = N;
    while (lo < hi) { int m = (lo + hi) >> 1; if (batch[m] < g) lo = m + 1; else hi = m; }
    int lo2 = lo; hi = N;
    while (lo2 < hi) { int m = (lo2 + hi) >> 1; if (batch[m] < g + 1) lo2 = m + 1; else hi = m; }
    float cnt = fmaxf((float)(lo2 - lo), 1.0f);
    float v = pool[g * DD + j] / cnt;
    float sq = v * v;
    #pragma unroll
    for (int off = 32; off > 0; off >>= 1) sq += __shfl_down(sq, off, 64);
    float nrm = __shfl(sq, 0, 64);
    out[g * DD + j] = v / sqrtf(nrm);
}

extern "C" void kernel_launch(void* const* d_in, const int* in_sizes, int n_in,
                              void* d_out, int out_size, void* d_ws, size_t ws_size,
                              hipStream_t stream) {
    const int*   node_types = (const int*)d_in[0];
    const int*   edge_index = (const int*)d_in[1];
    const int*   batch      = (const int*)d_in[2];
    const float* emb        = (const float*)d_in[3];
    const float* W1 = (const float*)d_in[4];
    const float* b1 = (const float*)d_in[5];
    const float* W2 = (const float*)d_in[6];
    const float* b2 = (const float*)d_in[7];
    const float* W3 = (const float*)d_in[8];
    const float* b3 = (const float*)d_in[9];
    const int N = in_sizes[0];
    const int E = in_sizes[1] / 2;
    const int* row = edge_index;
    const int* col = edge_index + E;
    const long ND = (long)N * DD;
    const int B = (N + SCH - 1) / SCH;

    // workspace layout (16B-aligned chunks)
    char* p = (char*)d_ws;
    float* bufA   = (float*)p;            p += ND * sizeof(float);
    float* bufB   = (float*)p;            p += ND * sizeof(float);
    int*   srcidx = (int*)p;              p += (size_t)E * sizeof(int);
    float* dinv   = (float*)p;            p += (size_t)N * sizeof(float);
    int*   cnt    = (int*)p;              p += (size_t)N * sizeof(int);
    int*   part   = (int*)p;              p += (size_t)N * sizeof(int);
    int*   rowptr = (int*)p;              p += (size_t)(N + 4) * sizeof(int);
    int*   bsum   = (int*)p;              p += 256 * sizeof(int);
    float* pool   = (float*)p;            p += (size_t)NUM_GRAPHS * DD * sizeof(float);

    // ---- CSR build + norms ----
    hipMemsetAsync(cnt, 0, (size_t)N * sizeof(int), stream);
    k_cnt<<<(E + 255) / 256, 256, 0, stream>>>(col, cnt, E);
    k_dinv<<<(N + 255) / 256, 256, 0, stream>>>(cnt, dinv, N);
    k_scan1<<<B, 256, 0, stream>>>(cnt, part, bsum, N);
    k_scan2<<<1, 64, 0, stream>>>(bsum, rowptr, B, N, E);
    k_scan3<<<(N + 255) / 256, 256, 0, stream>>>(part, bsum, rowptr, N);
    hipMemsetAsync(cnt, 0, (size_t)N * sizeof(int), stream);
    k_fill<<<(E + 255) / 256, 256, 0, stream>>>(row, col, rowptr, cnt, srcidx, E);

    // ---- embed ----
    k_embed<<<(int)((ND + 255) / 256), 256, 0, stream>>>(node_types, emb, bufA, N);

    // ---- 3 GCN layers ----
    const float* Wv[3] = {W1, W2, W3};
    const float* bv[3] = {b1, b2, b3};
    float* cur = bufA; float* nxt = bufB;
    for (int l = 0; l < 3; ++l) {
        k_matmul_inplace<<<2048, 256, 0, stream>>>(cur, Wv[l], N);
        k_aggregate<<<(N + 3) / 4, 256, 0, stream>>>(rowptr, srcidx, dinv, cur, bv[l], nxt,
                                                     N, (l < 2) ? 1 : 0);
        float* tmp = cur; cur = nxt; nxt = tmp;
    }

    // ---- pool + normalize ----
    hipMemsetAsync(pool, 0, (size_t)(NUM_GRAPHS * DD) * sizeof(float), stream);
    k_pool<<<(N + 1023) / 1024, 256, 0, stream>>>(cur, batch, pool, N);
    k_final<<<NUM_GRAPHS, DD, 0, stream>>>(pool, batch, (float*)d_out, N);
}

// Round 3
// 563.675 us; speedup vs baseline: 7.6441x; 1.3877x over previous
//
#include <hip/hip_runtime.h>

#define DD 64
#define NUM_GRAPHS 64
#define SCH 1024   // elements scanned per block

// ---- ticket pass: tick[e] = slot of edge e at its target; cnt ends as in-degree ----
__global__ void k_ticket(const int* __restrict__ col, int* __restrict__ cnt,
                         int* __restrict__ tick, int E) {
    int e = blockIdx.x * blockDim.x + threadIdx.x;
    if (e < E) tick[e] = atomicAdd(&cnt[col[e]], 1);
}

__global__ void k_dinv(const int* __restrict__ cnt, float* __restrict__ dinv, int N) {
    int i = blockIdx.x * blockDim.x + threadIdx.x;
    if (i < N) dinv[i] = rsqrtf((float)cnt[i] + 1.0f);   // +1 = self loop
}

// ---- scan: cnt -> exclusive prefix (into rowptr), block sums in bsum ----
__global__ __launch_bounds__(256) void k_scan1(const int* __restrict__ cnt,
                                               int* __restrict__ rowptr,
                                               int* __restrict__ bsum, int N) {
    __shared__ int s[256];
    int tid = threadIdx.x;
    long base = (long)blockIdx.x * SCH + (long)tid * 4;
    int v[4]; int tot = 0;
    #pragma unroll
    for (int k = 0; k < 4; ++k) {
        long i = base + k;
        v[k] = (i < N) ? cnt[i] : 0;
        tot += v[k];
    }
    s[tid] = tot;
    __syncthreads();
    for (int off = 1; off < 256; off <<= 1) {
        int t = (tid >= off) ? s[tid - off] : 0;
        __syncthreads();
        s[tid] += t;
        __syncthreads();
    }
    if (tid == 255) bsum[blockIdx.x] = s[255];
    int excl = s[tid] - tot;
    #pragma unroll
    for (int k = 0; k < 4; ++k) {
        long i = base + k;
        if (i < N) rowptr[i] = excl;
        excl += v[k];
    }
}

__global__ void k_scan2(int* __restrict__ bsum, int* __restrict__ rowptr, int B, int N, int E) {
    if (blockIdx.x == 0 && threadIdx.x == 0) {
        int run = 0;
        for (int i = 0; i < B; ++i) { int t = bsum[i]; bsum[i] = run; run += t; }
        rowptr[N] = E;
    }
}

__global__ void k_scan3(int* __restrict__ rowptr, const int* __restrict__ bsum, int N) {
    long i = (long)blockIdx.x * blockDim.x + threadIdx.x;
    if (i < N) rowptr[i] += bsum[i / SCH];
}

// ---- atomic-free CSR fill via tickets ----
__global__ void k_fillscatter(const int* __restrict__ row, const int* __restrict__ col,
                              const int* __restrict__ rowptr, const int* __restrict__ tick,
                              int* __restrict__ srcidx, int E) {
    int e = blockIdx.x * blockDim.x + threadIdx.x;
    if (e >= E) return;
    srcidx[rowptr[col[e]] + tick[e]] = row[e];
}

// ---- embW1 = emb_table @ W1  (30 x 64, tiny) ----
__global__ void k_embW1(const float* __restrict__ emb, const float* __restrict__ W1,
                        float* __restrict__ embW1, int V) {
    __shared__ float er[DD];
    int v = blockIdx.x, j = threadIdx.x;
    er[j] = emb[v * DD + j];
    __syncthreads();
    float acc = 0.0f;
    #pragma unroll
    for (int d = 0; d < DD; ++d) acc += er[d] * W1[d * DD + j];
    embW1[v * DD + j] = acc;
}

// ---- layer-1 aggregate: h[i] = embW1[nt[i]]; OUT[c] = relu((Σ h[s]*dinv[s] + h[c]*dc)*dc + b) ----
__global__ __launch_bounds__(256) void k_aggregate1(const int* __restrict__ rowptr,
                                                    const int* __restrict__ srcidx,
                                                    const int* __restrict__ nt,
                                                    const float* __restrict__ dinv,
                                                    const float* __restrict__ embW1,
                                                    const float* __restrict__ b,
                                                    float* __restrict__ OUT, int N, int V) {
    __shared__ float ew[30 * DD];
    int tid = threadIdx.x;
    for (int k = tid; k < V * DD; k += 256) ew[k] = embW1[k];
    __syncthreads();
    int node = blockIdx.x * 4 + (tid >> 6);
    int j = tid & 63;
    if (node >= N) return;
    int s = rowptr[node], e = rowptr[node + 1];
    float acc = 0.0f;
    int k = s;
    for (; k + 3 < e; k += 4) {
        int s0 = srcidx[k], s1 = srcidx[k+1], s2 = srcidx[k+2], s3 = srcidx[k+3];
        int t0 = nt[s0], t1 = nt[s1], t2 = nt[s2], t3 = nt[s3];
        float d0 = dinv[s0], d1 = dinv[s1], d2 = dinv[s2], d3 = dinv[s3];
        acc += ew[t0 * DD + j] * d0 + ew[t1 * DD + j] * d1
             + ew[t2 * DD + j] * d2 + ew[t3 * DD + j] * d3;
    }
    for (; k < e; ++k) {
        int s0 = srcidx[k];
        acc += ew[nt[s0] * DD + j] * dinv[s0];
    }
    float dc = dinv[node];
    float v = (acc + ew[nt[node] * DD + j] * dc) * dc + b[j];
    OUT[(long)node * DD + j] = fmaxf(v, 0.0f);
}

// ---- in-place row transform with dinv pre-scale: X[i] <- (X[i] @ W) * dinv[i] ----
__global__ __launch_bounds__(256) void k_matmul_inplace(float* __restrict__ X,
                                                        const float* __restrict__ W,
                                                        const float* __restrict__ dinv, int N) {
    __shared__ float Ws[DD * DD];   // 16 KB
    __shared__ float xs[4][DD];
    int tid = threadIdx.x;
    for (int k = tid; k < DD * DD; k += 256) Ws[k] = W[k];
    int j = tid & 63, r = tid >> 6;
    long stride = (long)gridDim.x * 4;
    for (long base = (long)blockIdx.x * 4; base < N; base += stride) {
        long node = base + r;
        __syncthreads();
        xs[r][j] = (node < (long)N) ? X[node * DD + j] : 0.0f;
        __syncthreads();
        float acc = 0.0f;
        #pragma unroll
        for (int d = 0; d < DD; ++d) acc += xs[r][d] * Ws[d * DD + j];
        if (node < (long)N) X[node * DD + j] = acc * dinv[node];
    }
}

// ---- layers 2/3 aggregate (Hs pre-scaled by dinv):
//      OUT[c] = relu?((Σ Hs[src] + Hs[c]) * dinv[c] + b) ----
__global__ __launch_bounds__(256) void k_aggregate(const int* __restrict__ rowptr,
                                                   const int* __restrict__ srcidx,
                                                   const float* __restrict__ dinv,
                                                   const float* __restrict__ Hs,
                                                   const float* __restrict__ b,
                                                   float* __restrict__ OUT,
                                                   int N, int do_relu) {
    int node = blockIdx.x * 4 + (threadIdx.x >> 6);   // one wave per node
    int j = threadIdx.x & 63;
    if (node >= N) return;
    int s = rowptr[node], e = rowptr[node + 1];
    float acc = 0.0f;
    int k = s;
    for (; k + 3 < e; k += 4) {
        int s0 = srcidx[k], s1 = srcidx[k+1], s2 = srcidx[k+2], s3 = srcidx[k+3];
        float h0 = Hs[(long)s0 * DD + j];
        float h1 = Hs[(long)s1 * DD + j];
        float h2 = Hs[(long)s2 * DD + j];
        float h3 = Hs[(long)s3 * DD + j];
        acc += h0 + h1 + h2 + h3;
    }
    for (; k < e; ++k) acc += Hs[(long)srcidx[k] * DD + j];
    float v = (acc + Hs[(long)node * DD + j]) * dinv[node] + b[j];
    OUT[(long)node * DD + j] = do_relu ? fmaxf(v, 0.0f) : v;
}

// ---- pooling: batch sorted; running sum, flush on graph change ----
__global__ __launch_bounds__(256) void k_pool(const float* __restrict__ X,
                                              const int* __restrict__ batch,
                                              float* __restrict__ pool, int N) {
    const int CH = 1024;
    int j = threadIdx.x & 63, r = threadIdx.x >> 6;
    long base = (long)blockIdx.x * CH;
    if (base >= N) return;
    long end = base + CH; if (end > N) end = N;
    int cur = -1; float acc = 0.0f;
    for (long i = base + r; i < end; i += 4) {
        int g = batch[i];
        float v = X[i * DD + j];
        if (g != cur) {
            if (cur >= 0) atomicAdd(&pool[cur * DD + j], acc);
            cur = g; acc = v;
        } else {
            acc += v;
        }
    }
    if (cur >= 0) atomicAdd(&pool[cur * DD + j], acc);
}

// ---- final: mean + L2 normalize ----
__global__ void k_final(const float* __restrict__ pool, const int* __restrict__ batch,
                        float* __restrict__ out, int N) {
    int g = blockIdx.x, j = threadIdx.x;
    int lo = 0, hi = N;
    while (lo < hi) { int m = (lo + hi) >> 1; if (batch[m] < g) lo = m + 1; else hi = m; }
    int lo2 = lo; hi = N;
    while (lo2 < hi) { int m = (lo2 + hi) >> 1; if (batch[m] < g + 1) lo2 = m + 1; else hi = m; }
    float cnt = fmaxf((float)(lo2 - lo), 1.0f);
    float v = pool[g * DD + j] / cnt;
    float sq = v * v;
    #pragma unroll
    for (int off = 32; off > 0; off >>= 1) sq += __shfl_down(sq, off, 64);
    float nrm = __shfl(sq, 0, 64);
    out[g * DD + j] = v / sqrtf(nrm);
}

extern "C" void kernel_launch(void* const* d_in, const int* in_sizes, int n_in,
                              void* d_out, int out_size, void* d_ws, size_t ws_size,
                              hipStream_t stream) {
    const int*   node_types = (const int*)d_in[0];
    const int*   edge_index = (const int*)d_in[1];
    const int*   batch      = (const int*)d_in[2];
    const float* emb        = (const float*)d_in[3];
    const float* W1 = (const float*)d_in[4];
    const float* b1 = (const float*)d_in[5];
    const float* W2 = (const float*)d_in[6];
    const float* b2 = (const float*)d_in[7];
    const float* W3 = (const float*)d_in[8];
    const float* b3 = (const float*)d_in[9];
    const int N = in_sizes[0];
    const int E = in_sizes[1] / 2;
    const int V = in_sizes[3] / DD;
    const int* row = edge_index;
    const int* col = edge_index + E;
    const long ND = (long)N * DD;
    const int B = (N + SCH - 1) / SCH;

    // workspace layout
    char* p = (char*)d_ws;
    float* bufA   = (float*)p;            p += ND * sizeof(float);
    float* bufB   = (float*)p;            p += ND * sizeof(float);
    int*   srcidx = (int*)p;              p += (size_t)E * sizeof(int);
    int*   tick   = (int*)p;              p += (size_t)E * sizeof(int);
    float* dinv   = (float*)p;            p += (size_t)N * sizeof(float);
    int*   cnt    = (int*)p;              p += (size_t)N * sizeof(int);
    int*   rowptr = (int*)p;              p += (size_t)(N + 4) * sizeof(int);
    int*   bsum   = (int*)p;              p += 256 * sizeof(int);
    float* pool   = (float*)p;            p += (size_t)NUM_GRAPHS * DD * sizeof(float);
    float* embW1  = (float*)p;            p += (size_t)V * DD * sizeof(float);

    // ---- CSR build (single atomic pass) + norms ----
    hipMemsetAsync(cnt, 0, (size_t)N * sizeof(int), stream);
    k_ticket<<<(E + 255) / 256, 256, 0, stream>>>(col, cnt, tick, E);
    k_dinv<<<(N + 255) / 256, 256, 0, stream>>>(cnt, dinv, N);
    k_scan1<<<B, 256, 0, stream>>>(cnt, rowptr, bsum, N);
    k_scan2<<<1, 64, 0, stream>>>(bsum, rowptr, B, N, E);
    k_scan3<<<(N + 255) / 256, 256, 0, stream>>>(rowptr, bsum, N);
    k_fillscatter<<<(E + 255) / 256, 256, 0, stream>>>(row, col, rowptr, tick, srcidx, E);

    // ---- layer 1: embW1 gather-aggregate (no N x D matmul needed) ----
    k_embW1<<<V, DD, 0, stream>>>(emb, W1, embW1, V);
    k_aggregate1<<<(N + 3) / 4, 256, 0, stream>>>(rowptr, srcidx, node_types, dinv,
                                                  embW1, b1, bufA, N, V);

    // ---- layers 2,3 ----
    float* cur = bufA; float* nxt = bufB;
    const float* Wv[2] = {W2, W3};
    const float* bv[2] = {b2, b3};
    for (int l = 0; l < 2; ++l) {
        k_matmul_inplace<<<2048, 256, 0, stream>>>(cur, Wv[l], dinv, N);
        k_aggregate<<<(N + 3) / 4, 256, 0, stream>>>(rowptr, srcidx, dinv, cur, bv[l], nxt,
                                                     N, (l == 0) ? 1 : 0);
        float* tmp = cur; cur = nxt; nxt = tmp;
    }

    // ---- pool + normalize ----
    hipMemsetAsync(pool, 0, (size_t)(NUM_GRAPHS * DD) * sizeof(float), stream);
    k_pool<<<(N + 1023) / 1024, 256, 0, stream>>>(cur, batch, pool, N);
    k_final<<<NUM_GRAPHS, DD, 0, stream>>>(pool, batch, (float*)d_out, N);
}

// Round 4
// 433.334 us; speedup vs baseline: 9.9434x; 1.3008x over previous
//
#include <hip/hip_runtime.h>

#define DD 64
#define NUM_GRAPHS 64
#define SCH 1024   // elements scanned per block
#define AGG_BLOCKS 2048

// ---- ticket pass: tick[e] = slot of edge e at its target; cnt ends as in-degree ----
__global__ void k_ticket(const int* __restrict__ col, int* __restrict__ cnt,
                         int* __restrict__ tick, int E) {
    int e = blockIdx.x * blockDim.x + threadIdx.x;
    if (e < E) tick[e] = atomicAdd(&cnt[col[e]], 1);
}

// ---- dinv + packed per-node {node_type, dinv} ----
__global__ void k_dinv_pack(const int* __restrict__ cnt, const int* __restrict__ nt,
                            float* __restrict__ dinv, int2* __restrict__ pk, int N) {
    int i = blockIdx.x * blockDim.x + threadIdx.x;
    if (i >= N) return;
    float di = rsqrtf((float)cnt[i] + 1.0f);   // +1 = self loop
    dinv[i] = di;
    pk[i] = make_int2(nt[i], __float_as_int(di));
}

// ---- scan: cnt -> exclusive prefix (into rowptr), block sums in bsum ----
__global__ __launch_bounds__(256) void k_scan1(const int* __restrict__ cnt,
                                               int* __restrict__ rowptr,
                                               int* __restrict__ bsum, int N) {
    __shared__ int s[256];
    int tid = threadIdx.x;
    long base = (long)blockIdx.x * SCH + (long)tid * 4;
    int v[4]; int tot = 0;
    #pragma unroll
    for (int k = 0; k < 4; ++k) {
        long i = base + k;
        v[k] = (i < N) ? cnt[i] : 0;
        tot += v[k];
    }
    s[tid] = tot;
    __syncthreads();
    for (int off = 1; off < 256; off <<= 1) {
        int t = (tid >= off) ? s[tid - off] : 0;
        __syncthreads();
        s[tid] += t;
        __syncthreads();
    }
    if (tid == 255) bsum[blockIdx.x] = s[255];
    int excl = s[tid] - tot;
    #pragma unroll
    for (int k = 0; k < 4; ++k) {
        long i = base + k;
        if (i < N) rowptr[i] = excl;
        excl += v[k];
    }
}

__global__ void k_scan2(int* __restrict__ bsum, int* __restrict__ rowptr, int B, int N, int E) {
    if (blockIdx.x == 0 && threadIdx.x == 0) {
        int run = 0;
        for (int i = 0; i < B; ++i) { int t = bsum[i]; bsum[i] = run; run += t; }
        rowptr[N] = E;
    }
}

__global__ void k_scan3(int* __restrict__ rowptr, const int* __restrict__ bsum, int N) {
    long i = (long)blockIdx.x * blockDim.x + threadIdx.x;
    if (i < N) rowptr[i] += bsum[i / SCH];
}

// ---- atomic-free CSR fill via tickets ----
__global__ void k_fillscatter(const int* __restrict__ row, const int* __restrict__ col,
                              const int* __restrict__ rowptr, const int* __restrict__ tick,
                              int* __restrict__ srcidx, int E) {
    int e = blockIdx.x * blockDim.x + threadIdx.x;
    if (e >= E) return;
    srcidx[rowptr[col[e]] + tick[e]] = row[e];
}

// ---- embW1 = emb_table @ W1  (30 x 64, tiny) ----
__global__ void k_embW1(const float* __restrict__ emb, const float* __restrict__ W1,
                        float* __restrict__ embW1, int V) {
    __shared__ float er[DD];
    int v = blockIdx.x, j = threadIdx.x;
    er[j] = emb[v * DD + j];
    __syncthreads();
    float acc = 0.0f;
    #pragma unroll
    for (int d = 0; d < DD; ++d) acc += er[d] * W1[d * DD + j];
    embW1[v * DD + j] = acc;
}

// per-wave row @ W with W column cached in VGPRs (Wcol[d] = W[d][j])
__device__ __forceinline__ float rowmatmul(float v, const float* Wcol) {
    int vb = __float_as_int(v);
    float o0 = 0.f, o1 = 0.f, o2 = 0.f, o3 = 0.f;
    #pragma unroll
    for (int d = 0; d < DD; d += 4) {
        o0 = fmaf(__int_as_float(__builtin_amdgcn_readlane(vb, d + 0)), Wcol[d + 0], o0);
        o1 = fmaf(__int_as_float(__builtin_amdgcn_readlane(vb, d + 1)), Wcol[d + 1], o1);
        o2 = fmaf(__int_as_float(__builtin_amdgcn_readlane(vb, d + 2)), Wcol[d + 2], o2);
        o3 = fmaf(__int_as_float(__builtin_amdgcn_readlane(vb, d + 3)), Wcol[d + 3], o3);
    }
    return (o0 + o1) + (o2 + o3);
}

// ---- layer-1 fused: v = relu((Σ ew[nt[s]]*dinv[s] + ew[nt[c]]*dc)*dc + b1);
//      OUT[c] = (v @ W2) * dc   (Hs2, pre-scaled for next layer) ----
__global__ __launch_bounds__(256) void k_agg1_fused(const int* __restrict__ rowptr,
                                                    const int* __restrict__ srcidx,
                                                    const int2* __restrict__ pk,
                                                    const float* __restrict__ embW1,
                                                    const float* __restrict__ b1,
                                                    const float* __restrict__ W2,
                                                    float* __restrict__ OUT, int N, int V) {
    __shared__ float ew[30 * DD];
    int tid = threadIdx.x;
    for (int k = tid; k < V * DD; k += 256) ew[k] = embW1[k];
    __syncthreads();
    int j = tid & 63;
    float Wcol[DD];
    #pragma unroll
    for (int d = 0; d < DD; ++d) Wcol[d] = W2[d * DD + j];
    float bj = b1[j];
    int wave0 = blockIdx.x * 4 + (tid >> 6);
    int wstride = gridDim.x * 4;
    for (int node = __builtin_amdgcn_readfirstlane(wave0); node < N;
         node += wstride) {
        int s = rowptr[node], e = rowptr[node + 1];
        float acc = 0.0f;
        int k = s;
        for (; k + 3 < e; k += 4) {
            int s0 = srcidx[k], s1 = srcidx[k+1], s2 = srcidx[k+2], s3 = srcidx[k+3];
            int2 p0 = pk[s0], p1 = pk[s1], p2 = pk[s2], p3 = pk[s3];
            acc += ew[p0.x * DD + j] * __int_as_float(p0.y)
                 + ew[p1.x * DD + j] * __int_as_float(p1.y)
                 + ew[p2.x * DD + j] * __int_as_float(p2.y)
                 + ew[p3.x * DD + j] * __int_as_float(p3.y);
        }
        for (; k < e; ++k) {
            int2 p0 = pk[srcidx[k]];
            acc += ew[p0.x * DD + j] * __int_as_float(p0.y);
        }
        int2 pc = pk[node];
        float dc = __int_as_float(pc.y);
        float v = (acc + ew[pc.x * DD + j] * dc) * dc + bj;
        v = fmaxf(v, 0.0f);
        OUT[(long)node * DD + j] = rowmatmul(v, Wcol) * dc;
    }
}

// ---- layer-2 fused: v = relu((Σ Hs[s] + Hs[c])*dc + b2); OUT[c] = (v @ W3) * dc ----
__global__ __launch_bounds__(256) void k_agg2_fused(const int* __restrict__ rowptr,
                                                    const int* __restrict__ srcidx,
                                                    const float* __restrict__ dinv,
                                                    const float* __restrict__ Hs,
                                                    const float* __restrict__ b2,
                                                    const float* __restrict__ W3,
                                                    float* __restrict__ OUT, int N) {
    int tid = threadIdx.x;
    int j = tid & 63;
    float Wcol[DD];
    #pragma unroll
    for (int d = 0; d < DD; ++d) Wcol[d] = W3[d * DD + j];
    float bj = b2[j];
    int wave0 = blockIdx.x * 4 + (tid >> 6);
    int wstride = gridDim.x * 4;
    for (int node = __builtin_amdgcn_readfirstlane(wave0); node < N;
         node += wstride) {
        int s = rowptr[node], e = rowptr[node + 1];
        float acc = 0.0f;
        int k = s;
        for (; k + 3 < e; k += 4) {
            int s0 = srcidx[k], s1 = srcidx[k+1], s2 = srcidx[k+2], s3 = srcidx[k+3];
            acc += Hs[(long)s0 * DD + j] + Hs[(long)s1 * DD + j]
                 + Hs[(long)s2 * DD + j] + Hs[(long)s3 * DD + j];
        }
        for (; k < e; ++k) acc += Hs[(long)srcidx[k] * DD + j];
        float dc = dinv[node];
        float v = (acc + Hs[(long)node * DD + j]) * dc + bj;
        v = fmaxf(v, 0.0f);
        OUT[(long)node * DD + j] = rowmatmul(v, Wcol) * dc;
    }
}

// ---- layer-3: X3[c] = (Σ Hs[s] + Hs[c])*dc + b3  (no relu, no matmul) ----
__global__ __launch_bounds__(256) void k_agg3(const int* __restrict__ rowptr,
                                              const int* __restrict__ srcidx,
                                              const float* __restrict__ dinv,
                                              const float* __restrict__ Hs,
                                              const float* __restrict__ b3,
                                              float* __restrict__ OUT, int N) {
    int tid = threadIdx.x;
    int j = tid & 63;
    float bj = b3[j];
    int wave0 = blockIdx.x * 4 + (tid >> 6);
    int wstride = gridDim.x * 4;
    for (int node = __builtin_amdgcn_readfirstlane(wave0); node < N;
         node += wstride) {
        int s = rowptr[node], e = rowptr[node + 1];
        float acc = 0.0f;
        int k = s;
        for (; k + 3 < e; k += 4) {
            int s0 = srcidx[k], s1 = srcidx[k+1], s2 = srcidx[k+2], s3 = srcidx[k+3];
            acc += Hs[(long)s0 * DD + j] + Hs[(long)s1 * DD + j]
                 + Hs[(long)s2 * DD + j] + Hs[(long)s3 * DD + j];
        }
        for (; k < e; ++k) acc += Hs[(long)srcidx[k] * DD + j];
        float dc = dinv[node];
        OUT[(long)node * DD + j] = (acc + Hs[(long)node * DD + j]) * dc + bj;
    }
}

// ---- pooling: batch sorted; running sum, flush on graph change ----
__global__ __launch_bounds__(256) void k_pool(const float* __restrict__ X,
                                              const int* __restrict__ batch,
                                              float* __restrict__ pool, int N) {
    const int CH = 128;
    int j = threadIdx.x & 63, r = threadIdx.x >> 6;
    long base = (long)blockIdx.x * CH;
    if (base >= N) return;
    long end = base + CH; if (end > N) end = N;
    int cur = -1; float acc = 0.0f;
    for (long i = base + r; i < end; i += 4) {
        int g = batch[i];
        float v = X[i * DD + j];
        if (g != cur) {
            if (cur >= 0) atomicAdd(&pool[cur * DD + j], acc);
            cur = g; acc = v;
        } else {
            acc += v;
        }
    }
    if (cur >= 0) atomicAdd(&pool[cur * DD + j], acc);
}

// ---- final: mean + L2 normalize ----
__global__ void k_final(const float* __restrict__ pool, const int* __restrict__ batch,
                        float* __restrict__ out, int N) {
    int g = blockIdx.x, j = threadIdx.x;
    int lo = 0, hi = N;
    while (lo < hi) { int m = (lo + hi) >> 1; if (batch[m] < g) lo = m + 1; else hi = m; }
    int lo2 = lo; hi = N;
    while (lo2 < hi) { int m = (lo2 + hi) >> 1; if (batch[m] < g + 1) lo2 = m + 1; else hi = m; }
    float cnt = fmaxf((float)(lo2 - lo), 1.0f);
    float v = pool[g * DD + j] / cnt;
    float sq = v * v;
    #pragma unroll
    for (int off = 32; off > 0; off >>= 1) sq += __shfl_down(sq, off, 64);
    float nrm = __shfl(sq, 0, 64);
    out[g * DD + j] = v / sqrtf(nrm);
}

extern "C" void kernel_launch(void* const* d_in, const int* in_sizes, int n_in,
                              void* d_out, int out_size, void* d_ws, size_t ws_size,
                              hipStream_t stream) {
    const int*   node_types = (const int*)d_in[0];
    const int*   edge_index = (const int*)d_in[1];
    const int*   batch      = (const int*)d_in[2];
    const float* emb        = (const float*)d_in[3];
    const float* W1 = (const float*)d_in[4];
    const float* b1 = (const float*)d_in[5];
    const float* W2 = (const float*)d_in[6];
    const float* b2 = (const float*)d_in[7];
    const float* W3 = (const float*)d_in[8];
    const float* b3 = (const float*)d_in[9];
    const int N = in_sizes[0];
    const int E = in_sizes[1] / 2;
    const int V = in_sizes[3] / DD;
    const int* row = edge_index;
    const int* col = edge_index + E;
    const long ND = (long)N * DD;
    const int B = (N + SCH - 1) / SCH;

    // workspace layout
    char* p = (char*)d_ws;
    float* bufA   = (float*)p;            p += ND * sizeof(float);
    float* bufB   = (float*)p;            p += ND * sizeof(float);
    int*   srcidx = (int*)p;              p += (size_t)E * sizeof(int);
    int*   tick   = (int*)p;              p += (size_t)E * sizeof(int);
    float* dinv   = (float*)p;            p += (size_t)N * sizeof(float);
    int2*  pk     = (int2*)p;             p += (size_t)N * sizeof(int2);
    int*   cnt    = (int*)p;              p += (size_t)N * sizeof(int);
    int*   rowptr = (int*)p;              p += (size_t)(N + 4) * sizeof(int);
    int*   bsum   = (int*)p;              p += 256 * sizeof(int);
    float* pool   = (float*)p;            p += (size_t)NUM_GRAPHS * DD * sizeof(float);
    float* embW1  = (float*)p;            p += (size_t)V * DD * sizeof(float);

    // ---- CSR build (single atomic pass) + norms ----
    hipMemsetAsync(cnt, 0, (size_t)N * sizeof(int), stream);
    k_ticket<<<(E + 255) / 256, 256, 0, stream>>>(col, cnt, tick, E);
    k_dinv_pack<<<(N + 255) / 256, 256, 0, stream>>>(cnt, node_types, dinv, pk, N);
    k_scan1<<<B, 256, 0, stream>>>(cnt, rowptr, bsum, N);
    k_scan2<<<1, 64, 0, stream>>>(bsum, rowptr, B, N, E);
    k_scan3<<<(N + 255) / 256, 256, 0, stream>>>(rowptr, bsum, N);
    k_fillscatter<<<(E + 255) / 256, 256, 0, stream>>>(row, col, rowptr, tick, srcidx, E);

    // ---- layer 1 (embW1 gather) fused with @W2*dinv ----
    k_embW1<<<V, DD, 0, stream>>>(emb, W1, embW1, V);
    k_agg1_fused<<<AGG_BLOCKS, 256, 0, stream>>>(rowptr, srcidx, pk, embW1, b1, W2,
                                                 bufA, N, V);
    // ---- layer 2 fused with @W3*dinv ----
    k_agg2_fused<<<AGG_BLOCKS, 256, 0, stream>>>(rowptr, srcidx, dinv, bufA, b2, W3,
                                                 bufB, N);
    // ---- layer 3 ----
    k_agg3<<<AGG_BLOCKS, 256, 0, stream>>>(rowptr, srcidx, dinv, bufB, b3, bufA, N);

    // ---- pool + normalize ----
    hipMemsetAsync(pool, 0, (size_t)(NUM_GRAPHS * DD) * sizeof(float), stream);
    k_pool<<<(N + 127) / 128, 256, 0, stream>>>(bufA, batch, pool, N);
    k_final<<<NUM_GRAPHS, DD, 0, stream>>>(pool, batch, (float*)d_out, N);
}

// Round 5
// 406.850 us; speedup vs baseline: 10.5906x; 1.0651x over previous
//
#include <hip/hip_runtime.h>
#include <hip/hip_fp16.h>

#define DD 64
#define NUM_GRAPHS 64
#define SCH 1024   // elements scanned per block
#define AGG_BLOCKS 2048

// ---- ticket pass: tick[e] = slot of edge e at its target; cnt ends as in-degree ----
__global__ void k_ticket(const int* __restrict__ col, int* __restrict__ cnt,
                         int* __restrict__ tick, int E) {
    int e = blockIdx.x * blockDim.x + threadIdx.x;
    if (e < E) tick[e] = atomicAdd(&cnt[col[e]], 1);
}

// ---- dinv + packed per-node {node_type, dinv} ----
__global__ void k_dinv_pack(const int* __restrict__ cnt, const int* __restrict__ nt,
                            float* __restrict__ dinv, int2* __restrict__ pk, int N) {
    int i = blockIdx.x * blockDim.x + threadIdx.x;
    if (i >= N) return;
    float di = rsqrtf((float)cnt[i] + 1.0f);   // +1 = self loop
    dinv[i] = di;
    pk[i] = make_int2(nt[i], __float_as_int(di));
}

// ---- scan: cnt -> exclusive prefix (into rowptr), block sums in bsum ----
__global__ __launch_bounds__(256) void k_scan1(const int* __restrict__ cnt,
                                               int* __restrict__ rowptr,
                                               int* __restrict__ bsum, int N) {
    __shared__ int s[256];
    int tid = threadIdx.x;
    long base = (long)blockIdx.x * SCH + (long)tid * 4;
    int v[4]; int tot = 0;
    #pragma unroll
    for (int k = 0; k < 4; ++k) {
        long i = base + k;
        v[k] = (i < N) ? cnt[i] : 0;
        tot += v[k];
    }
    s[tid] = tot;
    __syncthreads();
    for (int off = 1; off < 256; off <<= 1) {
        int t = (tid >= off) ? s[tid - off] : 0;
        __syncthreads();
        s[tid] += t;
        __syncthreads();
    }
    if (tid == 255) bsum[blockIdx.x] = s[255];
    int excl = s[tid] - tot;
    #pragma unroll
    for (int k = 0; k < 4; ++k) {
        long i = base + k;
        if (i < N) rowptr[i] = excl;
        excl += v[k];
    }
}

__global__ void k_scan2(int* __restrict__ bsum, int* __restrict__ rowptr, int B, int N, int E) {
    if (blockIdx.x == 0 && threadIdx.x == 0) {
        int run = 0;
        for (int i = 0; i < B; ++i) { int t = bsum[i]; bsum[i] = run; run += t; }
        rowptr[N] = E;
    }
}

__global__ void k_scan3(int* __restrict__ rowptr, const int* __restrict__ bsum, int N) {
    long i = (long)blockIdx.x * blockDim.x + threadIdx.x;
    if (i < N) rowptr[i] += bsum[i / SCH];
}

// ---- atomic-free CSR fill via tickets ----
__global__ void k_fillscatter(const int* __restrict__ row, const int* __restrict__ col,
                              const int* __restrict__ rowptr, const int* __restrict__ tick,
                              int* __restrict__ srcidx, int E) {
    int e = blockIdx.x * blockDim.x + threadIdx.x;
    if (e >= E) return;
    srcidx[rowptr[col[e]] + tick[e]] = row[e];
}

// ---- embW1 = emb_table @ W1  (30 x 64, tiny) ----
__global__ void k_embW1(const float* __restrict__ emb, const float* __restrict__ W1,
                        float* __restrict__ embW1, int V) {
    __shared__ float er[DD];
    int v = blockIdx.x, j = threadIdx.x;
    er[j] = emb[v * DD + j];
    __syncthreads();
    float acc = 0.0f;
    #pragma unroll
    for (int d = 0; d < DD; ++d) acc += er[d] * W1[d * DD + j];
    embW1[v * DD + j] = acc;
}

// per-wave row @ W with W column cached in VGPRs (Wcol[d] = W[d][j])
__device__ __forceinline__ float rowmatmul(float v, const float* Wcol) {
    int vb = __float_as_int(v);
    float o0 = 0.f, o1 = 0.f, o2 = 0.f, o3 = 0.f;
    #pragma unroll
    for (int d = 0; d < DD; d += 4) {
        o0 = fmaf(__int_as_float(__builtin_amdgcn_readlane(vb, d + 0)), Wcol[d + 0], o0);
        o1 = fmaf(__int_as_float(__builtin_amdgcn_readlane(vb, d + 1)), Wcol[d + 1], o1);
        o2 = fmaf(__int_as_float(__builtin_amdgcn_readlane(vb, d + 2)), Wcol[d + 2], o2);
        o3 = fmaf(__int_as_float(__builtin_amdgcn_readlane(vb, d + 3)), Wcol[d + 3], o3);
    }
    return (o0 + o1) + (o2 + o3);
}

// ---- layer-1 fused: v = relu((Σ ew[nt[s]]*dinv[s] + ew[nt[c]]*dc)*dc + b1);
//      OUT[c] = fp16( (v @ W2) * dc )   (Hs2, pre-scaled for next layer) ----
__global__ __launch_bounds__(256) void k_agg1_fused(const int* __restrict__ rowptr,
                                                    const int* __restrict__ srcidx,
                                                    const int2* __restrict__ pk,
                                                    const float* __restrict__ embW1,
                                                    const float* __restrict__ b1,
                                                    const float* __restrict__ W2,
                                                    __half* __restrict__ OUT, int N, int V) {
    __shared__ float ew[30 * DD];
    int tid = threadIdx.x;
    for (int k = tid; k < V * DD; k += 256) ew[k] = embW1[k];
    __syncthreads();
    int j = tid & 63;
    float Wcol[DD];
    #pragma unroll
    for (int d = 0; d < DD; ++d) Wcol[d] = W2[d * DD + j];
    float bj = b1[j];
    int wave0 = blockIdx.x * 4 + (tid >> 6);
    int wstride = gridDim.x * 4;
    for (int node = __builtin_amdgcn_readfirstlane(wave0); node < N;
         node += wstride) {
        int s = rowptr[node], e = rowptr[node + 1];
        float acc = 0.0f;
        int k = s;
        for (; k + 3 < e; k += 4) {
            int s0 = srcidx[k], s1 = srcidx[k+1], s2 = srcidx[k+2], s3 = srcidx[k+3];
            int2 p0 = pk[s0], p1 = pk[s1], p2 = pk[s2], p3 = pk[s3];
            acc += ew[p0.x * DD + j] * __int_as_float(p0.y)
                 + ew[p1.x * DD + j] * __int_as_float(p1.y)
                 + ew[p2.x * DD + j] * __int_as_float(p2.y)
                 + ew[p3.x * DD + j] * __int_as_float(p3.y);
        }
        for (; k < e; ++k) {
            int2 p0 = pk[srcidx[k]];
            acc += ew[p0.x * DD + j] * __int_as_float(p0.y);
        }
        int2 pc = pk[node];
        float dc = __int_as_float(pc.y);
        float v = (acc + ew[pc.x * DD + j] * dc) * dc + bj;
        v = fmaxf(v, 0.0f);
        OUT[(long)node * DD + j] = __float2half(rowmatmul(v, Wcol) * dc);
    }
}

// ---- layer-2 fused: v = relu((Σ Hs[s] + Hs[c])*dc + b2); OUT[c] = fp16((v @ W3) * dc) ----
__global__ __launch_bounds__(256) void k_agg2_fused(const int* __restrict__ rowptr,
                                                    const int* __restrict__ srcidx,
                                                    const float* __restrict__ dinv,
                                                    const __half* __restrict__ Hs,
                                                    const float* __restrict__ b2,
                                                    const float* __restrict__ W3,
                                                    __half* __restrict__ OUT, int N) {
    int tid = threadIdx.x;
    int j = tid & 63;
    float Wcol[DD];
    #pragma unroll
    for (int d = 0; d < DD; ++d) Wcol[d] = W3[d * DD + j];
    float bj = b2[j];
    int wave0 = blockIdx.x * 4 + (tid >> 6);
    int wstride = gridDim.x * 4;
    for (int node = __builtin_amdgcn_readfirstlane(wave0); node < N;
         node += wstride) {
        int s = rowptr[node], e = rowptr[node + 1];
        float acc = 0.0f;
        int k = s;
        for (; k + 3 < e; k += 4) {
            int s0 = srcidx[k], s1 = srcidx[k+1], s2 = srcidx[k+2], s3 = srcidx[k+3];
            float h0 = __half2float(Hs[(long)s0 * DD + j]);
            float h1 = __half2float(Hs[(long)s1 * DD + j]);
            float h2 = __half2float(Hs[(long)s2 * DD + j]);
            float h3 = __half2float(Hs[(long)s3 * DD + j]);
            acc += (h0 + h1) + (h2 + h3);
        }
        for (; k < e; ++k) acc += __half2float(Hs[(long)srcidx[k] * DD + j]);
        float dc = dinv[node];
        float v = (acc + __half2float(Hs[(long)node * DD + j])) * dc + bj;
        v = fmaxf(v, 0.0f);
        OUT[(long)node * DD + j] = __float2half(rowmatmul(v, Wcol) * dc);
    }
}

// ---- layer-3: X3[c] = (Σ Hs[s] + Hs[c])*dc + b3  (no relu, no matmul), f32 out ----
__global__ __launch_bounds__(256) void k_agg3(const int* __restrict__ rowptr,
                                              const int* __restrict__ srcidx,
                                              const float* __restrict__ dinv,
                                              const __half* __restrict__ Hs,
                                              const float* __restrict__ b3,
                                              float* __restrict__ OUT, int N) {
    int tid = threadIdx.x;
    int j = tid & 63;
    float bj = b3[j];
    int wave0 = blockIdx.x * 4 + (tid >> 6);
    int wstride = gridDim.x * 4;
    for (int node = __builtin_amdgcn_readfirstlane(wave0); node < N;
         node += wstride) {
        int s = rowptr[node], e = rowptr[node + 1];
        float acc = 0.0f;
        int k = s;
        for (; k + 3 < e; k += 4) {
            int s0 = srcidx[k], s1 = srcidx[k+1], s2 = srcidx[k+2], s3 = srcidx[k+3];
            float h0 = __half2float(Hs[(long)s0 * DD + j]);
            float h1 = __half2float(Hs[(long)s1 * DD + j]);
            float h2 = __half2float(Hs[(long)s2 * DD + j]);
            float h3 = __half2float(Hs[(long)s3 * DD + j]);
            acc += (h0 + h1) + (h2 + h3);
        }
        for (; k < e; ++k) acc += __half2float(Hs[(long)srcidx[k] * DD + j]);
        float dc = dinv[node];
        OUT[(long)node * DD + j] = (acc + __half2float(Hs[(long)node * DD + j])) * dc + bj;
    }
}

// ---- pooling: batch sorted; running sum, flush on graph change ----
__global__ __launch_bounds__(256) void k_pool(const float* __restrict__ X,
                                              const int* __restrict__ batch,
                                              float* __restrict__ pool, int N) {
    const int CH = 128;
    int j = threadIdx.x & 63, r = threadIdx.x >> 6;
    long base = (long)blockIdx.x * CH;
    if (base >= N) return;
    long end = base + CH; if (end > N) end = N;
    int cur = -1; float acc = 0.0f;
    for (long i = base + r; i < end; i += 4) {
        int g = batch[i];
        float v = X[i * DD + j];
        if (g != cur) {
            if (cur >= 0) atomicAdd(&pool[cur * DD + j], acc);
            cur = g; acc = v;
        } else {
            acc += v;
        }
    }
    if (cur >= 0) atomicAdd(&pool[cur * DD + j], acc);
}

// ---- final: mean + L2 normalize ----
__global__ void k_final(const float* __restrict__ pool, const int* __restrict__ batch,
                        float* __restrict__ out, int N) {
    int g = blockIdx.x, j = threadIdx.x;
    int lo = 0, hi = N;
    while (lo < hi) { int m = (lo + hi) >> 1; if (batch[m] < g) lo = m + 1; else hi = m; }
    int lo2 = lo; hi = N;
    while (lo2 < hi) { int m = (lo2 + hi) >> 1; if (batch[m] < g + 1) lo2 = m + 1; else hi = m; }
    float cnt = fmaxf((float)(lo2 - lo), 1.0f);
    float v = pool[g * DD + j] / cnt;
    float sq = v * v;
    #pragma unroll
    for (int off = 32; off > 0; off >>= 1) sq += __shfl_down(sq, off, 64);
    float nrm = __shfl(sq, 0, 64);
    out[g * DD + j] = v / sqrtf(nrm);
}

extern "C" void kernel_launch(void* const* d_in, const int* in_sizes, int n_in,
                              void* d_out, int out_size, void* d_ws, size_t ws_size,
                              hipStream_t stream) {
    const int*   node_types = (const int*)d_in[0];
    const int*   edge_index = (const int*)d_in[1];
    const int*   batch      = (const int*)d_in[2];
    const float* emb        = (const float*)d_in[3];
    const float* W1 = (const float*)d_in[4];
    const float* b1 = (const float*)d_in[5];
    const float* W2 = (const float*)d_in[6];
    const float* b2 = (const float*)d_in[7];
    const float* W3 = (const float*)d_in[8];
    const float* b3 = (const float*)d_in[9];
    const int N = in_sizes[0];
    const int E = in_sizes[1] / 2;
    const int V = in_sizes[3] / DD;
    const int* row = edge_index;
    const int* col = edge_index + E;
    const long ND = (long)N * DD;
    const int B = (N + SCH - 1) / SCH;

    // workspace layout
    char* p = (char*)d_ws;
    __half* hsA   = (__half*)p;           p += ND * sizeof(__half);
    __half* hsB   = (__half*)p;           p += ND * sizeof(__half);
    float*  bufC  = (float*)p;            p += ND * sizeof(float);
    int*   srcidx = (int*)p;              p += (size_t)E * sizeof(int);
    int*   tick   = (int*)p;              p += (size_t)E * sizeof(int);
    float* dinv   = (float*)p;            p += (size_t)N * sizeof(float);
    int2*  pk     = (int2*)p;             p += (size_t)N * sizeof(int2);
    int*   cnt    = (int*)p;              p += (size_t)N * sizeof(int);
    int*   rowptr = (int*)p;              p += (size_t)(N + 4) * sizeof(int);
    int*   bsum   = (int*)p;              p += 256 * sizeof(int);
    float* pool   = (float*)p;            p += (size_t)NUM_GRAPHS * DD * sizeof(float);
    float* embW1  = (float*)p;            p += (size_t)V * DD * sizeof(float);

    // ---- CSR build (single atomic pass) + norms ----
    hipMemsetAsync(cnt, 0, (size_t)N * sizeof(int), stream);
    k_ticket<<<(E + 255) / 256, 256, 0, stream>>>(col, cnt, tick, E);
    k_dinv_pack<<<(N + 255) / 256, 256, 0, stream>>>(cnt, node_types, dinv, pk, N);
    k_scan1<<<B, 256, 0, stream>>>(cnt, rowptr, bsum, N);
    k_scan2<<<1, 64, 0, stream>>>(bsum, rowptr, B, N, E);
    k_scan3<<<(N + 255) / 256, 256, 0, stream>>>(rowptr, bsum, N);
    k_fillscatter<<<(E + 255) / 256, 256, 0, stream>>>(row, col, rowptr, tick, srcidx, E);

    // ---- layer 1 (embW1 gather) fused with @W2*dinv -> fp16 ----
    k_embW1<<<V, DD, 0, stream>>>(emb, W1, embW1, V);
    k_agg1_fused<<<AGG_BLOCKS, 256, 0, stream>>>(rowptr, srcidx, pk, embW1, b1, W2,
                                                 hsA, N, V);
    // ---- layer 2 fused with @W3*dinv -> fp16 ----
    k_agg2_fused<<<AGG_BLOCKS, 256, 0, stream>>>(rowptr, srcidx, dinv, hsA, b2, W3,
                                                 hsB, N);
    // ---- layer 3 -> f32 ----
    k_agg3<<<AGG_BLOCKS, 256, 0, stream>>>(rowptr, srcidx, dinv, hsB, b3, bufC, N);

    // ---- pool + normalize ----
    hipMemsetAsync(pool, 0, (size_t)(NUM_GRAPHS * DD) * sizeof(float), stream);
    k_pool<<<(N + 127) / 128, 256, 0, stream>>>(bufC, batch, pool, N);
    k_final<<<NUM_GRAPHS, DD, 0, stream>>>(pool, batch, (float*)d_out, N);
}

// Round 6
// 390.407 us; speedup vs baseline: 11.0367x; 1.0421x over previous
//
#include <hip/hip_runtime.h>
#include <hip/hip_fp16.h>

#define DD 64
#define NUM_GRAPHS 64
#define SCH 1024   // elements scanned per block
#define AGG_BLOCKS 2048

// ---- ticket pass: tick[e] = slot of edge e at its target; cnt ends as in-degree ----
__global__ void k_ticket(const int* __restrict__ col, int* __restrict__ cnt,
                         int* __restrict__ tick, int E) {
    int e = blockIdx.x * blockDim.x + threadIdx.x;
    if (e < E) tick[e] = atomicAdd(&cnt[col[e]], 1);
}

// ---- scan: cnt -> exclusive prefix (into rowptr), block sums in bsum.
//      Fused: dinv + packed per-node {node_type, dinv} ----
__global__ __launch_bounds__(256) void k_scan1(const int* __restrict__ cnt,
                                               int* __restrict__ rowptr,
                                               int* __restrict__ bsum,
                                               const int* __restrict__ nt,
                                               float* __restrict__ dinv,
                                               int2* __restrict__ pk, int N) {
    __shared__ int s[256];
    int tid = threadIdx.x;
    long base = (long)blockIdx.x * SCH + (long)tid * 4;
    int v[4]; int tot = 0;
    #pragma unroll
    for (int k = 0; k < 4; ++k) {
        long i = base + k;
        v[k] = (i < N) ? cnt[i] : 0;
        if (i < N) {
            float di = rsqrtf((float)v[k] + 1.0f);   // +1 = self loop
            dinv[i] = di;
            pk[i] = make_int2(nt[i], __float_as_int(di));
        }
        tot += v[k];
    }
    s[tid] = tot;
    __syncthreads();
    for (int off = 1; off < 256; off <<= 1) {
        int t = (tid >= off) ? s[tid - off] : 0;
        __syncthreads();
        s[tid] += t;
        __syncthreads();
    }
    if (tid == 255) bsum[blockIdx.x] = s[255];
    int excl = s[tid] - tot;
    #pragma unroll
    for (int k = 0; k < 4; ++k) {
        long i = base + k;
        if (i < N) rowptr[i] = excl;
        excl += v[k];
    }
}

__global__ void k_scan2(int* __restrict__ bsum, int* __restrict__ rowptr, int B, int N, int E) {
    if (blockIdx.x == 0 && threadIdx.x == 0) {
        int run = 0;
        for (int i = 0; i < B; ++i) { int t = bsum[i]; bsum[i] = run; run += t; }
        rowptr[N] = E;
    }
}

__global__ void k_scan3(int* __restrict__ rowptr, const int* __restrict__ bsum, int N) {
    long i = (long)blockIdx.x * blockDim.x + threadIdx.x;
    if (i < N) rowptr[i] += bsum[i / SCH];
}

// ---- atomic-free CSR fill via tickets ----
__global__ void k_fillscatter(const int* __restrict__ row, const int* __restrict__ col,
                              const int* __restrict__ rowptr, const int* __restrict__ tick,
                              int* __restrict__ srcidx, int E) {
    int e = blockIdx.x * blockDim.x + threadIdx.x;
    if (e >= E) return;
    srcidx[rowptr[col[e]] + tick[e]] = row[e];
}

// ---- per-edge operands in CSR order: epk[p] = pk[srcidx[p]]  (pk is L2-resident) ----
__global__ void k_buildepk(const int* __restrict__ srcidx, const int2* __restrict__ pk,
                           int2* __restrict__ epk, int E) {
    int i = blockIdx.x * blockDim.x + threadIdx.x;
    if (i < E) epk[i] = pk[srcidx[i]];
}

// ---- embW1 = emb_table @ W1  (30 x 64, tiny) ----
__global__ void k_embW1(const float* __restrict__ emb, const float* __restrict__ W1,
                        float* __restrict__ embW1, int V) {
    __shared__ float er[DD];
    int v = blockIdx.x, j = threadIdx.x;
    er[j] = emb[v * DD + j];
    __syncthreads();
    float acc = 0.0f;
    #pragma unroll
    for (int d = 0; d < DD; ++d) acc += er[d] * W1[d * DD + j];
    embW1[v * DD + j] = acc;
}

// per-wave row @ W with W column cached in VGPRs (Wcol[d] = W[d][j])
__device__ __forceinline__ float rowmatmul(float v, const float* Wcol) {
    int vb = __float_as_int(v);
    float o0 = 0.f, o1 = 0.f, o2 = 0.f, o3 = 0.f;
    #pragma unroll
    for (int d = 0; d < DD; d += 4) {
        o0 = fmaf(__int_as_float(__builtin_amdgcn_readlane(vb, d + 0)), Wcol[d + 0], o0);
        o1 = fmaf(__int_as_float(__builtin_amdgcn_readlane(vb, d + 1)), Wcol[d + 1], o1);
        o2 = fmaf(__int_as_float(__builtin_amdgcn_readlane(vb, d + 2)), Wcol[d + 2], o2);
        o3 = fmaf(__int_as_float(__builtin_amdgcn_readlane(vb, d + 3)), Wcol[d + 3], o3);
    }
    return (o0 + o1) + (o2 + o3);
}

// ---- layer-1 fused: v = relu((Σ ew[t_e]*d_e + ew[nt[c]]*dc)*dc + b1);
//      OUT[c] = fp16( (v @ W2) * dc )  — per-edge {t,d} from sequential epk ----
__global__ __launch_bounds__(256) void k_agg1_fused(const int* __restrict__ rowptr,
                                                    const int2* __restrict__ epk,
                                                    const int2* __restrict__ pk,
                                                    const float* __restrict__ embW1,
                                                    const float* __restrict__ b1,
                                                    const float* __restrict__ W2,
                                                    __half* __restrict__ OUT, int N, int V) {
    __shared__ float ew[30 * DD];
    int tid = threadIdx.x;
    for (int k = tid; k < V * DD; k += 256) ew[k] = embW1[k];
    __syncthreads();
    int j = tid & 63;
    float Wcol[DD];
    #pragma unroll
    for (int d = 0; d < DD; ++d) Wcol[d] = W2[d * DD + j];
    float bj = b1[j];
    int wave0 = blockIdx.x * 4 + (tid >> 6);
    int wstride = gridDim.x * 4;
    for (int node = __builtin_amdgcn_readfirstlane(wave0); node < N;
         node += wstride) {
        int s = rowptr[node], e = rowptr[node + 1];
        float acc = 0.0f;
        int k = s;
        for (; k + 7 < e; k += 8) {
            int2 p0 = epk[k],   p1 = epk[k+1], p2 = epk[k+2], p3 = epk[k+3];
            int2 p4 = epk[k+4], p5 = epk[k+5], p6 = epk[k+6], p7 = epk[k+7];
            acc += ew[p0.x * DD + j] * __int_as_float(p0.y)
                 + ew[p1.x * DD + j] * __int_as_float(p1.y)
                 + ew[p2.x * DD + j] * __int_as_float(p2.y)
                 + ew[p3.x * DD + j] * __int_as_float(p3.y);
            acc += ew[p4.x * DD + j] * __int_as_float(p4.y)
                 + ew[p5.x * DD + j] * __int_as_float(p5.y)
                 + ew[p6.x * DD + j] * __int_as_float(p6.y)
                 + ew[p7.x * DD + j] * __int_as_float(p7.y);
        }
        for (; k < e; ++k) {
            int2 p0 = epk[k];
            acc += ew[p0.x * DD + j] * __int_as_float(p0.y);
        }
        int2 pc = pk[node];
        float dc = __int_as_float(pc.y);
        float v = (acc + ew[pc.x * DD + j] * dc) * dc + bj;
        v = fmaxf(v, 0.0f);
        OUT[(long)node * DD + j] = __float2half(rowmatmul(v, Wcol) * dc);
    }
}

// ---- layer-2 fused: v = relu((Σ Hs[s] + Hs[c])*dc + b2); OUT[c] = fp16((v @ W3) * dc) ----
__global__ __launch_bounds__(256) void k_agg2_fused(const int* __restrict__ rowptr,
                                                    const int* __restrict__ srcidx,
                                                    const float* __restrict__ dinv,
                                                    const __half* __restrict__ Hs,
                                                    const float* __restrict__ b2,
                                                    const float* __restrict__ W3,
                                                    __half* __restrict__ OUT, int N) {
    int tid = threadIdx.x;
    int j = tid & 63;
    float Wcol[DD];
    #pragma unroll
    for (int d = 0; d < DD; ++d) Wcol[d] = W3[d * DD + j];
    float bj = b2[j];
    int wave0 = blockIdx.x * 4 + (tid >> 6);
    int wstride = gridDim.x * 4;
    for (int node = __builtin_amdgcn_readfirstlane(wave0); node < N;
         node += wstride) {
        int s = rowptr[node], e = rowptr[node + 1];
        float acc = 0.0f;
        int k = s;
        for (; k + 3 < e; k += 4) {
            int s0 = srcidx[k], s1 = srcidx[k+1], s2 = srcidx[k+2], s3 = srcidx[k+3];
            float h0 = __half2float(Hs[(long)s0 * DD + j]);
            float h1 = __half2float(Hs[(long)s1 * DD + j]);
            float h2 = __half2float(Hs[(long)s2 * DD + j]);
            float h3 = __half2float(Hs[(long)s3 * DD + j]);
            acc += (h0 + h1) + (h2 + h3);
        }
        for (; k < e; ++k) acc += __half2float(Hs[(long)srcidx[k] * DD + j]);
        float dc = dinv[node];
        float v = (acc + __half2float(Hs[(long)node * DD + j])) * dc + bj;
        v = fmaxf(v, 0.0f);
        OUT[(long)node * DD + j] = __float2half(rowmatmul(v, Wcol) * dc);
    }
}

// ---- layer-3: X3[c] = (Σ Hs[s] + Hs[c])*dc + b3  (no relu, no matmul), f32 out ----
__global__ __launch_bounds__(256) void k_agg3(const int* __restrict__ rowptr,
                                              const int* __restrict__ srcidx,
                                              const float* __restrict__ dinv,
                                              const __half* __restrict__ Hs,
                                              const float* __restrict__ b3,
                                              float* __restrict__ OUT, int N) {
    int tid = threadIdx.x;
    int j = tid & 63;
    float bj = b3[j];
    int wave0 = blockIdx.x * 4 + (tid >> 6);
    int wstride = gridDim.x * 4;
    for (int node = __builtin_amdgcn_readfirstlane(wave0); node < N;
         node += wstride) {
        int s = rowptr[node], e = rowptr[node + 1];
        float acc = 0.0f;
        int k = s;
        for (; k + 3 < e; k += 4) {
            int s0 = srcidx[k], s1 = srcidx[k+1], s2 = srcidx[k+2], s3 = srcidx[k+3];
            float h0 = __half2float(Hs[(long)s0 * DD + j]);
            float h1 = __half2float(Hs[(long)s1 * DD + j]);
            float h2 = __half2float(Hs[(long)s2 * DD + j]);
            float h3 = __half2float(Hs[(long)s3 * DD + j]);
            acc += (h0 + h1) + (h2 + h3);
        }
        for (; k < e; ++k) acc += __half2float(Hs[(long)srcidx[k] * DD + j]);
        float dc = dinv[node];
        OUT[(long)node * DD + j] = (acc + __half2float(Hs[(long)node * DD + j])) * dc + bj;
    }
}

// ---- pooling: batch sorted; running sum, flush on graph change ----
__global__ __launch_bounds__(256) void k_pool(const float* __restrict__ X,
                                              const int* __restrict__ batch,
                                              float* __restrict__ pool, int N) {
    const int CH = 128;
    int j = threadIdx.x & 63, r = threadIdx.x >> 6;
    long base = (long)blockIdx.x * CH;
    if (base >= N) return;
    long end = base + CH; if (end > N) end = N;
    int cur = -1; float acc = 0.0f;
    for (long i = base + r; i < end; i += 4) {
        int g = batch[i];
        float v = X[i * DD + j];
        if (g != cur) {
            if (cur >= 0) atomicAdd(&pool[cur * DD + j], acc);
            cur = g; acc = v;
        } else {
            acc += v;
        }
    }
    if (cur >= 0) atomicAdd(&pool[cur * DD + j], acc);
}

// ---- final: mean + L2 normalize ----
__global__ void k_final(const float* __restrict__ pool, const int* __restrict__ batch,
                        float* __restrict__ out, int N) {
    int g = blockIdx.x, j = threadIdx.x;
    int lo = 0, hi = N;
    while (lo < hi) { int m = (lo + hi) >> 1; if (batch[m] < g) lo = m + 1; else hi = m; }
    int lo2 = lo; hi = N;
    while (lo2 < hi) { int m = (lo2 + hi) >> 1; if (batch[m] < g + 1) lo2 = m + 1; else hi = m; }
    float cnt = fmaxf((float)(lo2 - lo), 1.0f);
    float v = pool[g * DD + j] / cnt;
    float sq = v * v;
    #pragma unroll
    for (int off = 32; off > 0; off >>= 1) sq += __shfl_down(sq, off, 64);
    float nrm = __shfl(sq, 0, 64);
    out[g * DD + j] = v / sqrtf(nrm);
}

extern "C" void kernel_launch(void* const* d_in, const int* in_sizes, int n_in,
                              void* d_out, int out_size, void* d_ws, size_t ws_size,
                              hipStream_t stream) {
    const int*   node_types = (const int*)d_in[0];
    const int*   edge_index = (const int*)d_in[1];
    const int*   batch      = (const int*)d_in[2];
    const float* emb        = (const float*)d_in[3];
    const float* W1 = (const float*)d_in[4];
    const float* b1 = (const float*)d_in[5];
    const float* W2 = (const float*)d_in[6];
    const float* b2 = (const float*)d_in[7];
    const float* W3 = (const float*)d_in[8];
    const float* b3 = (const float*)d_in[9];
    const int N = in_sizes[0];
    const int E = in_sizes[1] / 2;
    const int V = in_sizes[3] / DD;
    const int* row = edge_index;
    const int* col = edge_index + E;
    const long ND = (long)N * DD;
    const int B = (N + SCH - 1) / SCH;

    // workspace layout
    char* p = (char*)d_ws;
    __half* hsA   = (__half*)p;           p += ND * sizeof(__half);
    __half* hsB   = (__half*)p;           p += ND * sizeof(__half);
    float*  bufC  = (float*)p;            p += ND * sizeof(float);
    int*   srcidx = (int*)p;              p += (size_t)E * sizeof(int);
    int*   tick   = (int*)p;              p += (size_t)E * sizeof(int);
    int2*  epk    = (int2*)p;             p += (size_t)E * sizeof(int2);
    float* dinv   = (float*)p;            p += (size_t)N * sizeof(float);
    int2*  pk     = (int2*)p;             p += (size_t)N * sizeof(int2);
    int*   cnt    = (int*)p;              p += (size_t)N * sizeof(int);
    int*   rowptr = (int*)p;              p += (size_t)(N + 4) * sizeof(int);
    int*   bsum   = (int*)p;              p += 256 * sizeof(int);
    float* pool   = (float*)p;            p += (size_t)NUM_GRAPHS * DD * sizeof(float);
    float* embW1  = (float*)p;            p += (size_t)V * DD * sizeof(float);

    // ---- CSR build (single atomic pass) + norms ----
    hipMemsetAsync(cnt, 0, (size_t)N * sizeof(int), stream);
    k_ticket<<<(E + 255) / 256, 256, 0, stream>>>(col, cnt, tick, E);
    k_scan1<<<B, 256, 0, stream>>>(cnt, rowptr, bsum, node_types, dinv, pk, N);
    k_scan2<<<1, 64, 0, stream>>>(bsum, rowptr, B, N, E);
    k_scan3<<<(N + 255) / 256, 256, 0, stream>>>(rowptr, bsum, N);
    k_fillscatter<<<(E + 255) / 256, 256, 0, stream>>>(row, col, rowptr, tick, srcidx, E);
    k_buildepk<<<(E + 255) / 256, 256, 0, stream>>>(srcidx, pk, epk, E);

    // ---- layer 1 (embW1 gather, sequential epk) fused with @W2*dinv -> fp16 ----
    k_embW1<<<V, DD, 0, stream>>>(emb, W1, embW1, V);
    k_agg1_fused<<<AGG_BLOCKS, 256, 0, stream>>>(rowptr, epk, pk, embW1, b1, W2,
                                                 hsA, N, V);
    // ---- layer 2 fused with @W3*dinv -> fp16 ----
    k_agg2_fused<<<AGG_BLOCKS, 256, 0, stream>>>(rowptr, srcidx, dinv, hsA, b2, W3,
                                                 hsB, N);
    // ---- layer 3 -> f32 ----
    k_agg3<<<AGG_BLOCKS, 256, 0, stream>>>(rowptr, srcidx, dinv, hsB, b3, bufC, N);

    // ---- pool + normalize ----
    hipMemsetAsync(pool, 0, (size_t)(NUM_GRAPHS * DD) * sizeof(float), stream);
    k_pool<<<(N + 127) / 128, 256, 0, stream>>>(bufC, batch, pool, N);
    k_final<<<NUM_GRAPHS, DD, 0, stream>>>(pool, batch, (float*)d_out, N);
}

// Round 7
// 376.019 us; speedup vs baseline: 11.4590x; 1.0383x over previous
//
#include <hip/hip_runtime.h>
#include <hip/hip_fp16.h>

#define DD 64
#define NUM_GRAPHS 64
#define SCH 1024   // elements scanned per block
#define AGG_BLOCKS 2048

// ---- ticket pass: tick[e] = slot of edge e at its target; cnt ends as in-degree ----
__global__ void k_ticket(const int* __restrict__ col, int* __restrict__ cnt,
                         int* __restrict__ tick, int E) {
    int e = blockIdx.x * blockDim.x + threadIdx.x;
    if (e < E) tick[e] = atomicAdd(&cnt[col[e]], 1);
}

// ---- scan: cnt -> exclusive prefix (into rowptr); fused dinv + pk build ----
__global__ __launch_bounds__(256) void k_scan1(const int* __restrict__ cnt,
                                               int* __restrict__ rowptr,
                                               int* __restrict__ bsum,
                                               const int* __restrict__ nt,
                                               float* __restrict__ dinv,
                                               int2* __restrict__ pk, int N) {
    __shared__ int s[256];
    int tid = threadIdx.x;
    long base = (long)blockIdx.x * SCH + (long)tid * 4;
    int v[4]; int tot = 0;
    #pragma unroll
    for (int k = 0; k < 4; ++k) {
        long i = base + k;
        v[k] = (i < N) ? cnt[i] : 0;
        if (i < N) {
            float di = rsqrtf((float)v[k] + 1.0f);   // +1 = self loop
            dinv[i] = di;
            pk[i] = make_int2(nt[i], __float_as_int(di));
        }
        tot += v[k];
    }
    s[tid] = tot;
    __syncthreads();
    for (int off = 1; off < 256; off <<= 1) {
        int t = (tid >= off) ? s[tid - off] : 0;
        __syncthreads();
        s[tid] += t;
        __syncthreads();
    }
    if (tid == 255) bsum[blockIdx.x] = s[255];
    int excl = s[tid] - tot;
    #pragma unroll
    for (int k = 0; k < 4; ++k) {
        long i = base + k;
        if (i < N) rowptr[i] = excl;
        excl += v[k];
    }
}

__global__ void k_scan2(int* __restrict__ bsum, int* __restrict__ rowptr, int B, int N, int E) {
    if (blockIdx.x == 0 && threadIdx.x == 0) {
        int run = 0;
        for (int i = 0; i < B; ++i) { int t = bsum[i]; bsum[i] = run; run += t; }
        rowptr[N] = E;
    }
}

__global__ void k_scan3(int* __restrict__ rowptr, const int* __restrict__ bsum, int N) {
    long i = (long)blockIdx.x * blockDim.x + threadIdx.x;
    if (i < N) rowptr[i] += bsum[i / SCH];
}

// ---- atomic-free CSR fill via tickets ----
__global__ void k_fillscatter(const int* __restrict__ row, const int* __restrict__ col,
                              const int* __restrict__ rowptr, const int* __restrict__ tick,
                              int* __restrict__ srcidx, int E) {
    int e = blockIdx.x * blockDim.x + threadIdx.x;
    if (e >= E) return;
    srcidx[rowptr[col[e]] + tick[e]] = row[e];
}

// ---- per-edge operands in CSR order: epk[p] = pk[srcidx[p]]  (pk is L2-resident) ----
__global__ void k_buildepk(const int* __restrict__ srcidx, const int2* __restrict__ pk,
                           int2* __restrict__ epk, int E) {
    int i = blockIdx.x * blockDim.x + threadIdx.x;
    if (i < E) epk[i] = pk[srcidx[i]];
}

// ---- embW1 = emb_table @ W1  (30 x 64, tiny) ----
__global__ void k_embW1(const float* __restrict__ emb, const float* __restrict__ W1,
                        float* __restrict__ embW1, int V) {
    __shared__ float er[DD];
    int v = blockIdx.x, j = threadIdx.x;
    er[j] = emb[v * DD + j];
    __syncthreads();
    float acc = 0.0f;
    #pragma unroll
    for (int d = 0; d < DD; ++d) acc += er[d] * W1[d * DD + j];
    embW1[v * DD + j] = acc;
}

// per-wave row @ W with W column cached in VGPRs (Wcol[d] = W[d][j])
__device__ __forceinline__ float rowmatmul(float v, const float* Wcol) {
    int vb = __float_as_int(v);
    float o0 = 0.f, o1 = 0.f, o2 = 0.f, o3 = 0.f;
    #pragma unroll
    for (int d = 0; d < DD; d += 4) {
        o0 = fmaf(__int_as_float(__builtin_amdgcn_readlane(vb, d + 0)), Wcol[d + 0], o0);
        o1 = fmaf(__int_as_float(__builtin_amdgcn_readlane(vb, d + 1)), Wcol[d + 1], o1);
        o2 = fmaf(__int_as_float(__builtin_amdgcn_readlane(vb, d + 2)), Wcol[d + 2], o2);
        o3 = fmaf(__int_as_float(__builtin_amdgcn_readlane(vb, d + 3)), Wcol[d + 3], o3);
    }
    return (o0 + o1) + (o2 + o3);
}

// split-wave half2 gather-sum: lanes 0-31 fetch even edges, lanes 32-63 odd edges,
// each lane covers feature pair p = lane&31 via __half2. Result (combined across
// halves) is the full edge-sum for pair p, duplicated in both halves.
__device__ __forceinline__ float2 gather_sum_h2(const int* __restrict__ srcidx,
                                                const __half* __restrict__ Hs,
                                                int s, int e, int half_id, int p) {
    float ax = 0.f, ay = 0.f, bx = 0.f, by = 0.f;
    int k = s;
    if ((e - k) & 1) {
        int s0 = srcidx[k];
        if (!half_id) {
            float2 f = __half22float2(*(const __half2*)(Hs + (long)s0 * DD + 2 * p));
            ax += f.x; ay += f.y;
        }
        k++;
    }
    if ((e - k) & 2) {
        int s0 = srcidx[k], s1 = srcidx[k + 1];
        int sel = half_id ? s1 : s0;
        float2 f = __half22float2(*(const __half2*)(Hs + (long)sel * DD + 2 * p));
        ax += f.x; ay += f.y;
        k += 2;
    }
    for (; k < e; k += 4) {
        int s0 = srcidx[k], s1 = srcidx[k+1], s2 = srcidx[k+2], s3 = srcidx[k+3];
        int selA = half_id ? s1 : s0;
        int selB = half_id ? s3 : s2;
        float2 fA = __half22float2(*(const __half2*)(Hs + (long)selA * DD + 2 * p));
        float2 fB = __half22float2(*(const __half2*)(Hs + (long)selB * DD + 2 * p));
        ax += fA.x; ay += fA.y; bx += fB.x; by += fB.y;
    }
    ax += bx; ay += by;
    ax += __shfl_xor(ax, 32, 64);
    ay += __shfl_xor(ay, 32, 64);
    return make_float2(ax, ay);
}

// ---- layer-1 fused: v = relu((Σ ew[t_e]*d_e + ew[nt[c]]*dc)*dc + b1);
//      OUT[c] = fp16( (v @ W2) * dc )  — per-edge {t,d} from sequential epk ----
__global__ __launch_bounds__(256) void k_agg1_fused(const int* __restrict__ rowptr,
                                                    const int2* __restrict__ epk,
                                                    const int2* __restrict__ pk,
                                                    const float* __restrict__ embW1,
                                                    const float* __restrict__ b1,
                                                    const float* __restrict__ W2,
                                                    __half* __restrict__ OUT, int N, int V) {
    __shared__ float ew[30 * DD];
    int tid = threadIdx.x;
    for (int k = tid; k < V * DD; k += 256) ew[k] = embW1[k];
    __syncthreads();
    int j = tid & 63;
    float Wcol[DD];
    #pragma unroll
    for (int d = 0; d < DD; ++d) Wcol[d] = W2[d * DD + j];
    float bj = b1[j];
    int wave0 = blockIdx.x * 4 + (tid >> 6);
    int wstride = gridDim.x * 4;
    for (int node = __builtin_amdgcn_readfirstlane(wave0); node < N;
         node += wstride) {
        int s = rowptr[node], e = rowptr[node + 1];
        float acc = 0.0f;
        int k = s;
        for (; k + 7 < e; k += 8) {
            int2 p0 = epk[k],   p1 = epk[k+1], p2 = epk[k+2], p3 = epk[k+3];
            int2 p4 = epk[k+4], p5 = epk[k+5], p6 = epk[k+6], p7 = epk[k+7];
            acc += ew[p0.x * DD + j] * __int_as_float(p0.y)
                 + ew[p1.x * DD + j] * __int_as_float(p1.y)
                 + ew[p2.x * DD + j] * __int_as_float(p2.y)
                 + ew[p3.x * DD + j] * __int_as_float(p3.y);
            acc += ew[p4.x * DD + j] * __int_as_float(p4.y)
                 + ew[p5.x * DD + j] * __int_as_float(p5.y)
                 + ew[p6.x * DD + j] * __int_as_float(p6.y)
                 + ew[p7.x * DD + j] * __int_as_float(p7.y);
        }
        for (; k < e; ++k) {
            int2 p0 = epk[k];
            acc += ew[p0.x * DD + j] * __int_as_float(p0.y);
        }
        int2 pc = pk[node];
        float dc = __int_as_float(pc.y);
        float v = (acc + ew[pc.x * DD + j] * dc) * dc + bj;
        v = fmaxf(v, 0.0f);
        OUT[(long)node * DD + j] = __float2half(rowmatmul(v, Wcol) * dc);
    }
}

// ---- layer-2: split-wave half2 gather; v=relu((Σ+self)*dc+b2); OUT=fp16((v@W3)*dc) ----
__global__ __launch_bounds__(256) void k_agg2_fused(const int* __restrict__ rowptr,
                                                    const int* __restrict__ srcidx,
                                                    const float* __restrict__ dinv,
                                                    const __half* __restrict__ Hs,
                                                    const float* __restrict__ b2,
                                                    const float* __restrict__ W3,
                                                    __half* __restrict__ OUT, int N) {
    int tid = threadIdx.x;
    int lane = tid & 63;
    int half_id = lane >> 5, p = lane & 31;
    float Wcol[DD];
    #pragma unroll
    for (int d = 0; d < DD; ++d) Wcol[d] = W3[d * DD + lane];
    float2 b2p = *(const float2*)(b2 + 2 * p);
    int wave0 = blockIdx.x * 4 + (tid >> 6);
    int wstride = gridDim.x * 4;
    for (int node = __builtin_amdgcn_readfirstlane(wave0); node < N;
         node += wstride) {
        int s = rowptr[node], e = rowptr[node + 1];
        float2 acc = gather_sum_h2(srcidx, Hs, s, e, half_id, p);
        float dc = dinv[node];
        float2 self = __half22float2(*(const __half2*)(Hs + (long)node * DD + 2 * p));
        float vx = fmaxf((acc.x + self.x) * dc + b2p.x, 0.f);
        float vy = fmaxf((acc.y + self.y) * dc + b2p.y, 0.f);
        int vxb = __float_as_int(vx), vyb = __float_as_int(vy);
        float o0 = 0.f, o1 = 0.f, o2 = 0.f, o3 = 0.f;
        #pragma unroll
        for (int d = 0; d < DD; d += 4) {
            o0 = fmaf(__int_as_float(__builtin_amdgcn_readlane(vxb, d >> 1)), Wcol[d + 0], o0);
            o1 = fmaf(__int_as_float(__builtin_amdgcn_readlane(vyb, d >> 1)), Wcol[d + 1], o1);
            o2 = fmaf(__int_as_float(__builtin_amdgcn_readlane(vxb, (d >> 1) + 1)), Wcol[d + 2], o2);
            o3 = fmaf(__int_as_float(__builtin_amdgcn_readlane(vyb, (d >> 1) + 1)), Wcol[d + 3], o3);
        }
        float o = (o0 + o1) + (o2 + o3);
        OUT[(long)node * DD + lane] = __float2half(o * dc);
    }
}

// ---- layer-3 fused with pooling: contiguous node chunks per wave (batch sorted);
//      v = (Σ+self)*dc + b3; running per-graph sum, atomic flush on graph change ----
__global__ __launch_bounds__(256) void k_agg3_pool(const int* __restrict__ rowptr,
                                                   const int* __restrict__ srcidx,
                                                   const float* __restrict__ dinv,
                                                   const __half* __restrict__ Hs,
                                                   const float* __restrict__ b3,
                                                   const int* __restrict__ batch,
                                                   float* __restrict__ pool,
                                                   int N, int chunk) {
    int tid = threadIdx.x;
    int lane = tid & 63;
    int half_id = lane >> 5, p = lane & 31;
    int w = __builtin_amdgcn_readfirstlane(blockIdx.x * 4 + (tid >> 6));
    int start = w * chunk;
    if (start >= N) return;
    int endn = min(N, start + chunk);
    float2 b3p = *(const float2*)(b3 + 2 * p);
    int gcur = batch[start];
    float2 pacc = make_float2(0.f, 0.f);
    for (int node = start; node < endn; ++node) {
        int s = rowptr[node], e = rowptr[node + 1];
        float2 acc = gather_sum_h2(srcidx, Hs, s, e, half_id, p);
        float dc = dinv[node];
        float2 self = __half22float2(*(const __half2*)(Hs + (long)node * DD + 2 * p));
        float vx = (acc.x + self.x) * dc + b3p.x;
        float vy = (acc.y + self.y) * dc + b3p.y;
        int g = batch[node];
        if (g != gcur) {
            if (!half_id) {
                atomicAdd(&pool[gcur * DD + 2 * p],     pacc.x);
                atomicAdd(&pool[gcur * DD + 2 * p + 1], pacc.y);
            }
            gcur = g;
            pacc = make_float2(vx, vy);
        } else {
            pacc.x += vx; pacc.y += vy;
        }
    }
    if (!half_id) {
        atomicAdd(&pool[gcur * DD + 2 * p],     pacc.x);
        atomicAdd(&pool[gcur * DD + 2 * p + 1], pacc.y);
    }
}

// ---- final: mean + L2 normalize ----
__global__ void k_final(const float* __restrict__ pool, const int* __restrict__ batch,
                        float* __restrict__ out, int N) {
    int g = blockIdx.x, j = threadIdx.x;
    int lo = 0, hi = N;
    while (lo < hi) { int m = (lo + hi) >> 1; if (batch[m] < g) lo = m + 1; else hi = m; }
    int lo2 = lo; hi = N;
    while (lo2 < hi) { int m = (lo2 + hi) >> 1; if (batch[m] < g + 1) lo2 = m + 1; else hi = m; }
    float cnt = fmaxf((float)(lo2 - lo), 1.0f);
    float v = pool[g * DD + j] / cnt;
    float sq = v * v;
    #pragma unroll
    for (int off = 32; off > 0; off >>= 1) sq += __shfl_down(sq, off, 64);
    float nrm = __shfl(sq, 0, 64);
    out[g * DD + j] = v / sqrtf(nrm);
}

extern "C" void kernel_launch(void* const* d_in, const int* in_sizes, int n_in,
                              void* d_out, int out_size, void* d_ws, size_t ws_size,
                              hipStream_t stream) {
    const int*   node_types = (const int*)d_in[0];
    const int*   edge_index = (const int*)d_in[1];
    const int*   batch      = (const int*)d_in[2];
    const float* emb        = (const float*)d_in[3];
    const float* W1 = (const float*)d_in[4];
    const float* b1 = (const float*)d_in[5];
    const float* W2 = (const float*)d_in[6];
    const float* b2 = (const float*)d_in[7];
    const float* W3 = (const float*)d_in[8];
    const float* b3 = (const float*)d_in[9];
    const int N = in_sizes[0];
    const int E = in_sizes[1] / 2;
    const int V = in_sizes[3] / DD;
    const int* row = edge_index;
    const int* col = edge_index + E;
    const long ND = (long)N * DD;
    const int B = (N + SCH - 1) / SCH;

    // workspace layout
    char* p = (char*)d_ws;
    __half* hsA   = (__half*)p;           p += ND * sizeof(__half);
    __half* hsB   = (__half*)p;           p += ND * sizeof(__half);
    int*   srcidx = (int*)p;              p += (size_t)E * sizeof(int);
    int*   tick   = (int*)p;              p += (size_t)E * sizeof(int);
    int2*  epk    = (int2*)p;             p += (size_t)E * sizeof(int2);
    float* dinv   = (float*)p;            p += (size_t)N * sizeof(float);
    int2*  pk     = (int2*)p;             p += (size_t)N * sizeof(int2);
    int*   cnt    = (int*)p;              p += (size_t)N * sizeof(int);
    int*   rowptr = (int*)p;              p += (size_t)(N + 4) * sizeof(int);
    int*   bsum   = (int*)p;              p += 256 * sizeof(int);
    float* pool   = (float*)p;            p += (size_t)NUM_GRAPHS * DD * sizeof(float);
    float* embW1  = (float*)p;            p += (size_t)V * DD * sizeof(float);

    // ---- CSR build (single atomic pass) + norms ----
    hipMemsetAsync(cnt, 0, (size_t)N * sizeof(int), stream);
    k_ticket<<<(E + 255) / 256, 256, 0, stream>>>(col, cnt, tick, E);
    k_scan1<<<B, 256, 0, stream>>>(cnt, rowptr, bsum, node_types, dinv, pk, N);
    k_scan2<<<1, 64, 0, stream>>>(bsum, rowptr, B, N, E);
    k_scan3<<<(N + 255) / 256, 256, 0, stream>>>(rowptr, bsum, N);
    k_fillscatter<<<(E + 255) / 256, 256, 0, stream>>>(row, col, rowptr, tick, srcidx, E);
    k_buildepk<<<(E + 255) / 256, 256, 0, stream>>>(srcidx, pk, epk, E);

    // ---- layer 1 (embW1 gather, sequential epk) fused with @W2*dinv -> fp16 ----
    k_embW1<<<V, DD, 0, stream>>>(emb, W1, embW1, V);
    k_agg1_fused<<<AGG_BLOCKS, 256, 0, stream>>>(rowptr, epk, pk, embW1, b1, W2,
                                                 hsA, N, V);
    // ---- layer 2 fused with @W3*dinv -> fp16 ----
    k_agg2_fused<<<AGG_BLOCKS, 256, 0, stream>>>(rowptr, srcidx, dinv, hsA, b2, W3,
                                                 hsB, N);
    // ---- layer 3 fused with pooling ----
    hipMemsetAsync(pool, 0, (size_t)(NUM_GRAPHS * DD) * sizeof(float), stream);
    const int totalWaves = AGG_BLOCKS * 4;
    const int chunk = (N + totalWaves - 1) / totalWaves;
    k_agg3_pool<<<AGG_BLOCKS, 256, 0, stream>>>(rowptr, srcidx, dinv, hsB, b3, batch,
                                                pool, N, chunk);
    // ---- normalize ----
    k_final<<<NUM_GRAPHS, DD, 0, stream>>>(pool, batch, (float*)d_out, N);
}